// Round 15
// baseline (27.928 us; speedup 1.0000x reference)
//
#include <hip/hip_runtime.h>
#include <hip/hip_bf16.h>

#define DEVINL __device__ __forceinline__

using bf16 = __hip_bfloat16;
typedef __attribute__((ext_vector_type(8))) short short8v;
typedef __attribute__((ext_vector_type(4))) float float4v;

DEVINL unsigned short f2bu(float x) { return __bfloat16_as_ushort(__float2bfloat16(x)); }

DEVINL short8v pk8(float4 a, float4 b) {
    union { unsigned short u[8]; short8v v; } r;
    r.u[0] = f2bu(a.x); r.u[1] = f2bu(a.y); r.u[2] = f2bu(a.z); r.u[3] = f2bu(a.w);
    r.u[4] = f2bu(b.x); r.u[5] = f2bu(b.y); r.u[6] = f2bu(b.z); r.u[7] = f2bu(b.w);
    return r.v;
}

// ===========================================================================
// K0: convert Wp (fp32 [128][384]) -> bf16 workspace (once per call).
// Validated r11 (launch cost ~= 0; beat r10's inline cvt).
// ===========================================================================
__global__ __launch_bounds__(256) void cvt_wp_kernel(
    const float* __restrict__ Wp, unsigned short* __restrict__ wpB) {
    int gid = blockIdx.x * 256 + threadIdx.x;  // 12288 float4s
    float4 v = ((const float4*)Wp)[gid];
    union { unsigned short u[4]; uint2 d2; } pk;
    pk.u[0] = f2bu(v.x); pk.u[1] = f2bu(v.y);
    pk.u[2] = f2bu(v.z); pk.u[3] = f2bu(v.w);
    *(uint2*)&wpB[gid * 4] = pk.d2;
}

// ===========================================================================
// Main fused kernel = r14 byte-identical EXCEPT __launch_bounds__(512, 6):
// forces VGPR <= ~85 => 6 waves/SIMD => 3 blocks/CU (LDS 46.9KB x 3 = 140.7
// <= 160KB). Single-variable occupancy probe:
//   helps   => we were VGPR-capped at 1-2 blocks/CU (latency thesis holds)
//   hurts   => spill cost > TLP; r11/r14 ~23.5us is the structural floor.
// r14's prefix/suffix Z kept (smallest live-reg footprint of the Z variants).
// 512 thr = 8 waves, 16 samples/block, grid = N/16 = 512.
// Algebra (validated r2-r14); MFMA layouts m89-verified.
// Lessons: r5 no packed fp32; r9 no wide raw-float hoists; r12 no
//   shuffle-gather phase-2; r9/r13 no M/M2 cndmask chains.
// ===========================================================================

template <int BASE, int CNT, int OTH, int LVL>
DEVINL void do_lvl_mfma(const unsigned short (*featT)[16][72],
                        int lane, int t,
                        const short8v bA[2], const short8v bC[2],
                        float4v binit, unsigned short (*finS)[392]) {
    float4v zero = (float4v){0.f, 0.f, 0.f, 0.f};
    float4v aa[CNT], cc[CNT];
    int kq8 = (lane >> 4) * 8;
    int sl = lane & 15;
#pragma unroll
    for (int j = 0; j < CNT; ++j) {
        const unsigned short* base = &featT[BASE + j][sl][kq8];
        short8v a0 = *(const short8v*)base;
        short8v a1 = *(const short8v*)(base + 32);
        aa[j] = __builtin_amdgcn_mfma_f32_16x16x32_bf16(a0, bA[0], binit, 0, 0, 0);
        aa[j] = __builtin_amdgcn_mfma_f32_16x16x32_bf16(a1, bA[1], aa[j], 0, 0, 0);
        cc[j] = __builtin_amdgcn_mfma_f32_16x16x32_bf16(a0, bC[0], zero, 0, 0, 0);
        cc[j] = __builtin_amdgcn_mfma_f32_16x16x32_bf16(a1, bC[1], cc[j], 0, 0, 0);
    }
    float bet = binit[0];

#pragma unroll
    for (int r = 0; r < 4; ++r) {
        // exclusive prefix/suffix maxes of c over joints: exact max_{k!=j}
        float pre[CNT], suf[CNT];
        pre[0] = -3e38f;
#pragma unroll
        for (int j = 1; j < CNT; ++j) pre[j] = fmaxf(pre[j - 1], cc[j - 1][r]);
        suf[CNT - 1] = -3e38f;
#pragma unroll
        for (int j = CNT - 2; j >= 0; --j) suf[j] = fmaxf(suf[j + 1], cc[j + 1][r]);

        float zs = 0.f;
#pragma unroll
        for (int j = 0; j < CNT; ++j) {
            float G = fmaxf(fmaxf(pre[j], suf[j]), 0.f);  // v_max3 candidate
            zs += fmaxf(aa[j][r] + G, 0.f);
        }
        float Mall = fmaxf(pre[CNT - 1], cc[CNT - 1][r]);  // max over all c
        zs += (float)OTH * fmaxf(bet + Mall, 0.f);         // other-side shared Z
        int s = (lane >> 4) * 4 + r;   // C row = sample, all 16 real
        finS[s][LVL * 128 + 64 + t] = f2bu(zs * (1.f / 17.f));
    }
}

__global__ __launch_bounds__(512, 6) void hse_one_kernel(
    const float* __restrict__ kp, const float* __restrict__ sc,
    const float* __restrict__ W0, const float* __restrict__ b0,
    const float* __restrict__ W1, const float* __restrict__ b1,
    const float* __restrict__ W2, const float* __restrict__ b2,
    const float* __restrict__ We, const float* __restrict__ be,
    const unsigned short* __restrict__ wpB, const float* __restrict__ bp,
    float* __restrict__ out) {
    __shared__ float4 Praw[16][17];              // 4.35 KB [sample][joint]{x,y,s,-}
    __shared__ unsigned short featT[13][16][72]; // 30.0 KB [joint][sample][d]
    __shared__ unsigned short finS[16][392];     // 12.5 KB [sample][feature]

    int tid = threadIdx.x;
    int w = tid >> 6;
    int lane = tid & 63;
    int sampBase = blockIdx.x * 16;

    // ---- wave-local staging: half 0 -> sample 2w, half 1 -> sample 2w+1 ----
    int jj = lane & 31;
    int halfId = lane >> 5;
    int sMine = 2 * w + halfId;
    float xx = 0.f, yy = 0.f;
    if (jj < 17) {
        size_t base = (size_t)(sampBase + sMine) * 17 + jj;
        float2 xy = *(const float2*)(kp + base * 2);
        float ss = sc[base];
        xx = xy.x; yy = xy.y;
        Praw[sMine][jj] = make_float4(xx, yy, ss, 0.f);
    }

    // ---- hoisted phase-2/3 operands: We loads overlap kp staging ----
    int tile = w >> 1, parity = w & 1;
    int t2 = tile * 16 + (lane & 15);
    int kq8 = (lane >> 4) * 8;
    short8v bA[2], bC[2];
#pragma unroll
    for (int k = 0; k < 2; ++k) {
        int dbase = k * 32 + kq8;
        const float* r1 = We + t2 * 128 + dbase;
        const float* r2 = We + t2 * 128 + 64 + dbase;
        float4 x0 = *(const float4*)r1;
        float4 x1 = *(const float4*)(r1 + 4);
        float4 y0 = *(const float4*)r2;
        float4 y1 = *(const float4*)(r2 + 4);
        float4 d0 = make_float4(x0.x - y0.x, x0.y - y0.y, x0.z - y0.z, x0.w - y0.w);
        float4 d1 = make_float4(x1.x - y1.x, x1.y - y1.y, x1.z - y1.z, x1.w - y1.w);
        bA[k] = pk8(d0, d1);
        bC[k] = pk8(y0, y1);
    }
    float bet = be[t2];
    int o3 = w * 16 + (lane & 15);
    float bvout = bp[o3];

    // ---- ONE width-32 butterfly for both samples; then 8 broadcasts ----
    float mnx = (jj < 17) ? xx : 1e30f, mxx = (jj < 17) ? xx : -1e30f;
    float mny = (jj < 17) ? yy : 1e30f, mxy = (jj < 17) ? yy : -1e30f;
#pragma unroll
    for (int off = 16; off; off >>= 1) {
        mnx = fminf(mnx, __shfl_xor(mnx, off, 32));
        mxx = fmaxf(mxx, __shfl_xor(mxx, off, 32));
        mny = fminf(mny, __shfl_xor(mny, off, 32));
        mxy = fmaxf(mxy, __shfl_xor(mxy, off, 32));
    }
    float ixl = 1.f / (mxx - mnx + 1e-6f);
    float iyl = 1.f / (mxy - mny + 1e-6f);
    float mnx_h[2], mny_h[2], ix_h[2], iy_h[2];
    mnx_h[0] = __shfl(mnx, 0);  mnx_h[1] = __shfl(mnx, 32);
    mny_h[0] = __shfl(mny, 0);  mny_h[1] = __shfl(mny, 32);
    ix_h[0] = __shfl(ixl, 0);   ix_h[1] = __shfl(ixl, 32);
    iy_h[0] = __shfl(iyl, 0);   iy_h[1] = __shfl(iyl, 32);

    // =============== phase 1: wave = samples {2w, 2w+1}, lane = d ==========
    {
        constexpr int JL[13]  = {0, 5, 6, 11, 12, 7, 8, 13, 14, 9, 10, 15, 16};
        constexpr int LEV[13] = {0, 0, 0, 0,  0,  1, 1, 1,  1,  2, 2,  2,  2};
        const float* Wls[3] = {W0, W1, W2};
        const float* bls[3] = {b0, b1, b2};
        float wx[3], wy[3], wsv[3], wb[3];
#pragma unroll
        for (int L = 0; L < 3; ++L) {
            wx[L] = Wls[L][lane * 3 + 0];
            wy[L] = Wls[L][lane * 3 + 1];
            wsv[L] = Wls[L][lane * 3 + 2];
            wb[L] = bls[L][lane];
        }

#pragma unroll
        for (int half = 0; half < 2; ++half) {
            int s = 2 * w + half;
            float mnxh = mnx_h[half], mnyh = mny_h[half];
            float ixh = ix_h[half], iyh = iy_h[half];

            float mj[13], sj[13];
            float msum[3] = {0.f, 0.f, 0.f};
#pragma unroll
            for (int q = 0; q < 13; ++q) {
                int j = JL[q];
                int L = LEV[q];
                float4 pv = Praw[s][j];                  // b128 broadcast
                float px = (pv.x - mnxh) * ixh;          // same-wave RAW
                float py = (pv.y - mnyh) * iyh;
                float ps = pv.z;
                float h = fmaxf(px * wx[L] + py * wy[L] + ps * wsv[L] + wb[L], 0.f);
                float m = h * ps;
                mj[q] = m;
                sj[q] = ps;
                msum[L] += m;
            }
#pragma unroll
            for (int q = 0; q < 13; ++q) {
                featT[q][s][lane] = f2bu((msum[LEV[q]] - mj[q]) * sj[q]);
            }
            // H-part: Hsum_L = (CNT_L - 1) * msum_L (validated r6)
            finS[s][0 * 128 + lane] = f2bu(4.f * msum[0] * (1.f / 17.f));
            finS[s][1 * 128 + lane] = f2bu(3.f * msum[1] * (1.f / 17.f));
            finS[s][2 * 128 + lane] = f2bu(3.f * msum[2] * (1.f / 17.f));
        }
    }
    __syncthreads();

    // ============ phase 2: wave = (t-tile, level-set), MFMA a/c ============
    {
        float4v binit = (float4v){bet, bet, bet, bet};
        if (parity == 0) {
            do_lvl_mfma<0, 5, 4, 0>(featT, lane, t2, bA, bC, binit, finS);
        } else {
            do_lvl_mfma<5, 4, 9, 1>(featT, lane, t2, bA, bC, binit, finS);
            do_lvl_mfma<9, 4, 4, 2>(featT, lane, t2, bA, bC, binit, finS);
        }
    }
    __syncthreads();

    // ====== phase 3: wave = n-tile w; out = finS @ wpB^T + bp (MFMA) =======
    {
        const short8v* bptr = (const short8v*)(wpB + (size_t)o3 * 384 + kq8);
        float4v acc = (float4v){bvout, bvout, bvout, bvout};
#pragma unroll
        for (int kt = 0; kt < 12; ++kt) {
            short8v a = *(const short8v*)&finS[lane & 15][kt * 32 + kq8];
            short8v b = bptr[kt * 4];
            acc = __builtin_amdgcn_mfma_f32_16x16x32_bf16(a, b, acc, 0, 0, 0);
        }
        int srow = (lane >> 4) * 4;
#pragma unroll
        for (int r = 0; r < 4; ++r) {
            out[(size_t)(sampBase + srow + r) * 128 + o3] = acc[r];
        }
    }
}

// ===========================================================================
// Fallback: validated round-2 fused kernel (used only if ws too small).
// ===========================================================================
template <int LI, int CNT, int OTH>
DEVINL void do_level_f(int w, int lane,
                       const float* __restrict__ Wl, const float* __restrict__ bl,
                       float mnx, float ix, float mny, float iy,
                       const float (*Praw)[17][3],
                       float (*featS)[64][8],
                       const float2 (*WW)[64],
                       const float* beS,
                       float (*finS)[384]) {
    constexpr int SUBJ[3][5] = {{0, 5, 6, 11, 12}, {7, 8, 13, 14, 16}, {9, 10, 15, 16, 16}};
    float w0 = Wl[lane * 3 + 0], w1 = Wl[lane * 3 + 1], w2 = Wl[lane * 3 + 2], bb = bl[lane];
    float mj[CNT], sj[CNT];
    float msum = 0.f;
#pragma unroll
    for (int jj = 0; jj < CNT; ++jj) {
        int j = SUBJ[LI][jj];
        float px = (Praw[w][j][0] - mnx) * ix;
        float py = (Praw[w][j][1] - mny) * iy;
        float ps = Praw[w][j][2];
        float h = fmaxf(px * w0 + py * w1 + ps * w2 + bb, 0.f);
        float m = h * ps;
        mj[jj] = m; sj[jj] = ps; msum += m;
    }
#pragma unroll
    for (int jj = 0; jj < CNT; ++jj) featS[w][lane][jj] = (msum - mj[jj]) * sj[jj];
    float Hsum = (float)(CNT - 1) * msum;
    __syncthreads();
    float a_[CNT], c_[CNT];
    float bet = beS[lane];
#pragma unroll
    for (int jj = 0; jj < CNT; ++jj) { a_[jj] = bet; c_[jj] = 0.f; }
#pragma unroll 4
    for (int d = 0; d < 64; ++d) {
        float2 wv = WW[d][lane];
        const float* fr = &featS[w][d][0];
        float4 f4 = *(const float4*)fr;
        float f[5];
        f[0] = f4.x; f[1] = f4.y; f[2] = f4.z; f[3] = f4.w; f[4] = 0.f;
        if constexpr (CNT > 4) f[4] = fr[4];
#pragma unroll
        for (int jj = 0; jj < CNT; ++jj) {
            a_[jj] = fmaf(wv.x, f[jj], a_[jj]);
            c_[jj] = fmaf(wv.y, f[jj], c_[jj]);
        }
    }
    __syncthreads();
    float zsum = 0.f;
#pragma unroll
    for (int jj = 0; jj < CNT; ++jj) {
        float z = fmaxf(a_[jj], 0.f);
#pragma unroll
        for (int kk = 0; kk < CNT; ++kk)
            if (kk != jj) z = fmaxf(z, a_[jj] + c_[kk]);
        zsum += z;
    }
    float zo = 0.f;
#pragma unroll
    for (int kk = 0; kk < CNT; ++kk) zo = fmaxf(zo, bet + c_[kk]);
    zsum += (float)OTH * zo;
    finS[w][LI * 128 + lane] = Hsum * (1.f / 17.f);
    finS[w][LI * 128 + 64 + lane] = zsum * (1.f / 17.f);
}

__global__ __launch_bounds__(256) void hse_fused_kernel(
    const float* __restrict__ kp, const float* __restrict__ sc,
    const float* __restrict__ W0, const float* __restrict__ b0,
    const float* __restrict__ W1, const float* __restrict__ b1,
    const float* __restrict__ W2, const float* __restrict__ b2,
    const float* __restrict__ We, const float* __restrict__ be,
    const float* __restrict__ Wp, const float* __restrict__ bp,
    float* __restrict__ out) {
    __shared__ float2 WW[64][64];
    __shared__ float beS[64];
    __shared__ float Praw[4][17][3];
    __shared__ float featS[4][64][8];
    __shared__ float finS[4][384];

    int tid = threadIdx.x;
    int w = tid >> 6;
    int lane = tid & 63;
    int sample = blockIdx.x * 4 + w;

    for (int i = tid; i < 4096; i += 256) {
        int t = i >> 6, d = i & 63;
        float wA = We[t * 128 + d];
        float wB = We[t * 128 + 64 + d];
        WW[d][t] = make_float2(wA - wB, wB);
    }
    if (tid < 64) beS[tid] = be[tid];
    if (lane < 17) {
        size_t base = (size_t)sample * 17 + lane;
        float2 xy = *(const float2*)(kp + base * 2);
        Praw[w][lane][0] = xy.x;
        Praw[w][lane][1] = xy.y;
        Praw[w][lane][2] = sc[base];
    }
    __syncthreads();

    float mnx = 1e30f, mxx = -1e30f, mny = 1e30f, mxy = -1e30f;
    for (int j = 0; j < 17; ++j) {
        float x = Praw[w][j][0], y = Praw[w][j][1];
        mnx = fminf(mnx, x); mxx = fmaxf(mxx, x);
        mny = fminf(mny, y); mxy = fmaxf(mxy, y);
    }
    float ix = 1.f / (mxx - mnx + 1e-6f);
    float iy = 1.f / (mxy - mny + 1e-6f);

    do_level_f<0, 5, 4>(w, lane, W0, b0, mnx, ix, mny, iy, Praw, featS, WW, beS, finS);
    do_level_f<1, 4, 9>(w, lane, W1, b1, mnx, ix, mny, iy, Praw, featS, WW, beS, finS);
    do_level_f<2, 4, 4>(w, lane, W2, b2, mnx, ix, mny, iy, Praw, featS, WW, beS, finS);
    __syncthreads();

    float acc0 = bp[lane];
    float acc1 = bp[64 + lane];
    const float* r0 = Wp + (size_t)lane * 384;
    const float* r1 = Wp + (size_t)(64 + lane) * 384;
    const float* fv = finS[w];
#pragma unroll 8
    for (int e = 0; e < 384; e += 4) {
        float4 wa = *(const float4*)(r0 + e);
        float4 wb = *(const float4*)(r1 + e);
        float4 ffv = *(const float4*)(fv + e);
        acc0 = fmaf(wa.x, ffv.x, acc0);
        acc0 = fmaf(wa.y, ffv.y, acc0);
        acc0 = fmaf(wa.z, ffv.z, acc0);
        acc0 = fmaf(wa.w, ffv.w, acc0);
        acc1 = fmaf(wb.x, ffv.x, acc1);
        acc1 = fmaf(wb.y, ffv.y, acc1);
        acc1 = fmaf(wb.z, ffv.z, acc1);
        acc1 = fmaf(wb.w, ffv.w, acc1);
    }
    out[(size_t)sample * 128 + lane] = acc0;
    out[(size_t)sample * 128 + 64 + lane] = acc1;
}

extern "C" void kernel_launch(void* const* d_in, const int* in_sizes, int n_in,
                              void* d_out, int out_size, void* d_ws, size_t ws_size,
                              hipStream_t stream) {
    const float* kp = (const float*)d_in[0];
    const float* sc = (const float*)d_in[1];
    const float* W0 = (const float*)d_in[2];
    const float* b0 = (const float*)d_in[3];
    const float* W1 = (const float*)d_in[4];
    const float* b1 = (const float*)d_in[5];
    const float* W2 = (const float*)d_in[6];
    const float* b2 = (const float*)d_in[7];
    const float* We = (const float*)d_in[8];
    const float* be = (const float*)d_in[9];
    const float* Wp = (const float*)d_in[10];
    const float* bp = (const float*)d_in[11];
    float* out = (float*)d_out;

    int N = in_sizes[0] / 34;  // keypoints N*17*2 -> 8192
    size_t need = 49152 * sizeof(unsigned short);

    if (ws_size >= need) {
        unsigned short* wpB = (unsigned short*)d_ws;
        hipLaunchKernelGGL(cvt_wp_kernel, dim3(48), dim3(256), 0, stream, Wp, wpB);
        hipLaunchKernelGGL(hse_one_kernel, dim3(N / 16), dim3(512), 0, stream,
                           kp, sc, W0, b0, W1, b1, W2, b2, We, be, wpB, bp, out);
    } else {
        hipLaunchKernelGGL(hse_fused_kernel, dim3(N / 4), dim3(256), 0, stream,
                           kp, sc, W0, b0, W1, b1, W2, b2, We, be, Wp, bp, out);
    }
}

// Round 16
// 23.363 us; speedup vs baseline: 1.1954x; 1.1954x over previous
//
#include <hip/hip_runtime.h>
#include <hip/hip_bf16.h>

#define DEVINL __device__ __forceinline__

using bf16 = __hip_bfloat16;
typedef __attribute__((ext_vector_type(8))) short short8v;
typedef __attribute__((ext_vector_type(4))) float float4v;

DEVINL unsigned short f2bu(float x) { return __bfloat16_as_ushort(__float2bfloat16(x)); }

DEVINL short8v pk8(float4 a, float4 b) {
    union { unsigned short u[8]; short8v v; } r;
    r.u[0] = f2bu(a.x); r.u[1] = f2bu(a.y); r.u[2] = f2bu(a.z); r.u[3] = f2bu(a.w);
    r.u[4] = f2bu(b.x); r.u[5] = f2bu(b.y); r.u[6] = f2bu(b.z); r.u[7] = f2bu(b.w);
    return r.v;
}

// ===========================================================================
// K0: convert Wp (fp32 [128][384]) -> bf16 workspace (once per call).
// Validated r11 (launch cost ~= 0; beat r10's inline cvt).
// ===========================================================================
__global__ __launch_bounds__(256) void cvt_wp_kernel(
    const float* __restrict__ Wp, unsigned short* __restrict__ wpB) {
    int gid = blockIdx.x * 256 + threadIdx.x;  // 12288 float4s
    float4 v = ((const float4*)Wp)[gid];
    union { unsigned short u[4]; uint2 d2; } pk;
    pk.u[0] = f2bu(v.x); pk.u[1] = f2bu(v.y);
    pk.u[2] = f2bu(v.z); pk.u[3] = f2bu(v.w);
    *(uint2*)&wpB[gid * 4] = pk.d2;
}

// ===========================================================================
// Main fused kernel — EXACT r11 (session optimum, 23.54us validated).
// 512 thr = 8 waves, 16 samples/block, grid = N/16 = 512.
// r12-r15 probes all regressed or flat:
//   r12 wave-local phase2 (shuffle-gather): +11.8us (redundant-lane Z)
//   r13 M/M2 Z + lb(512,4): +1.7us (cndmask chains / VGPR cap)
//   r14 prefix/suffix Z: +0.3us (noise; issue cuts don't move the wall)
//   r15 lb(512,6): +4.4us (spills > TLP)
// => latency-structural floor at ~23.5us for this (and every tested) shape.
// Algebra (validated r2-r11): H_u = msum - m_u; msg = relu(a_j + c_k);
//   cross-level c==0; other-side a==be; OTH joints share max_k relu(be+c_k).
// MFMA layouts (m89-verified): A/B row/col = l&15, k = (l>>4)*8+j;
//   C row = (l>>4)*4+reg, col = l&15.
// ===========================================================================

template <int BASE, int CNT, int OTH, int LVL>
DEVINL void do_lvl_mfma(const unsigned short (*featT)[16][72],
                        int lane, int t,
                        const short8v bA[2], const short8v bC[2],
                        float4v binit, unsigned short (*finS)[392]) {
    float4v zero = (float4v){0.f, 0.f, 0.f, 0.f};
    float4v aa[CNT], cc[CNT];
    int kq8 = (lane >> 4) * 8;
    int sl = lane & 15;
#pragma unroll
    for (int j = 0; j < CNT; ++j) {
        const unsigned short* base = &featT[BASE + j][sl][kq8];
        short8v a0 = *(const short8v*)base;
        short8v a1 = *(const short8v*)(base + 32);
        aa[j] = __builtin_amdgcn_mfma_f32_16x16x32_bf16(a0, bA[0], binit, 0, 0, 0);
        aa[j] = __builtin_amdgcn_mfma_f32_16x16x32_bf16(a1, bA[1], aa[j], 0, 0, 0);
        cc[j] = __builtin_amdgcn_mfma_f32_16x16x32_bf16(a0, bC[0], zero, 0, 0, 0);
        cc[j] = __builtin_amdgcn_mfma_f32_16x16x32_bf16(a1, bC[1], cc[j], 0, 0, 0);
    }
    float bet = binit[0];
#pragma unroll
    for (int r = 0; r < 4; ++r) {
        float a_[CNT], c_[CNT];
#pragma unroll
        for (int j = 0; j < CNT; ++j) { a_[j] = aa[j][r]; c_[j] = cc[j][r]; }
        float zs = 0.f;
#pragma unroll
        for (int j = 0; j < CNT; ++j) {
            float z = fmaxf(a_[j], 0.f);
#pragma unroll
            for (int k = 0; k < CNT; ++k) {
                if (k != j) z = fmaxf(z, a_[j] + c_[k]);
            }
            zs += z;
        }
        float zo = 0.f;
#pragma unroll
        for (int k = 0; k < CNT; ++k) zo = fmaxf(zo, bet + c_[k]);
        zs += (float)OTH * zo;
        int s = (lane >> 4) * 4 + r;   // C row = sample, all 16 real
        finS[s][LVL * 128 + 64 + t] = f2bu(zs * (1.f / 17.f));
    }
}

__global__ __launch_bounds__(512) void hse_one_kernel(
    const float* __restrict__ kp, const float* __restrict__ sc,
    const float* __restrict__ W0, const float* __restrict__ b0,
    const float* __restrict__ W1, const float* __restrict__ b1,
    const float* __restrict__ W2, const float* __restrict__ b2,
    const float* __restrict__ We, const float* __restrict__ be,
    const unsigned short* __restrict__ wpB, const float* __restrict__ bp,
    float* __restrict__ out) {
    __shared__ float4 Praw[16][17];              // 4.35 KB [sample][joint]{x,y,s,-}
    __shared__ unsigned short featT[13][16][72]; // 30.0 KB [joint][sample][d]
    __shared__ unsigned short finS[16][392];     // 12.5 KB [sample][feature]

    int tid = threadIdx.x;
    int w = tid >> 6;
    int lane = tid & 63;
    int sampBase = blockIdx.x * 16;

    // ---- wave-local staging: half 0 -> sample 2w, half 1 -> sample 2w+1 ----
    int jj = lane & 31;
    int halfId = lane >> 5;
    int sMine = 2 * w + halfId;
    float xx = 0.f, yy = 0.f;
    if (jj < 17) {
        size_t base = (size_t)(sampBase + sMine) * 17 + jj;
        float2 xy = *(const float2*)(kp + base * 2);
        float ss = sc[base];
        xx = xy.x; yy = xy.y;
        Praw[sMine][jj] = make_float4(xx, yy, ss, 0.f);
    }

    // ---- hoisted phase-2/3 operands: We loads overlap kp staging ----
    int tile = w >> 1, parity = w & 1;
    int t2 = tile * 16 + (lane & 15);
    int kq8 = (lane >> 4) * 8;
    short8v bA[2], bC[2];
#pragma unroll
    for (int k = 0; k < 2; ++k) {
        int dbase = k * 32 + kq8;
        const float* r1 = We + t2 * 128 + dbase;
        const float* r2 = We + t2 * 128 + 64 + dbase;
        float4 x0 = *(const float4*)r1;
        float4 x1 = *(const float4*)(r1 + 4);
        float4 y0 = *(const float4*)r2;
        float4 y1 = *(const float4*)(r2 + 4);
        float4 d0 = make_float4(x0.x - y0.x, x0.y - y0.y, x0.z - y0.z, x0.w - y0.w);
        float4 d1 = make_float4(x1.x - y1.x, x1.y - y1.y, x1.z - y1.z, x1.w - y1.w);
        bA[k] = pk8(d0, d1);
        bC[k] = pk8(y0, y1);
    }
    float bet = be[t2];
    int o3 = w * 16 + (lane & 15);
    float bvout = bp[o3];

    // ---- ONE width-32 butterfly for both samples; then 8 broadcasts ----
    float mnx = (jj < 17) ? xx : 1e30f, mxx = (jj < 17) ? xx : -1e30f;
    float mny = (jj < 17) ? yy : 1e30f, mxy = (jj < 17) ? yy : -1e30f;
#pragma unroll
    for (int off = 16; off; off >>= 1) {
        mnx = fminf(mnx, __shfl_xor(mnx, off, 32));
        mxx = fmaxf(mxx, __shfl_xor(mxx, off, 32));
        mny = fminf(mny, __shfl_xor(mny, off, 32));
        mxy = fmaxf(mxy, __shfl_xor(mxy, off, 32));
    }
    float ixl = 1.f / (mxx - mnx + 1e-6f);
    float iyl = 1.f / (mxy - mny + 1e-6f);
    float mnx_h[2], mny_h[2], ix_h[2], iy_h[2];
    mnx_h[0] = __shfl(mnx, 0);  mnx_h[1] = __shfl(mnx, 32);
    mny_h[0] = __shfl(mny, 0);  mny_h[1] = __shfl(mny, 32);
    ix_h[0] = __shfl(ixl, 0);   ix_h[1] = __shfl(ixl, 32);
    iy_h[0] = __shfl(iyl, 0);   iy_h[1] = __shfl(iyl, 32);

    // =============== phase 1: wave = samples {2w, 2w+1}, lane = d ==========
    {
        constexpr int JL[13]  = {0, 5, 6, 11, 12, 7, 8, 13, 14, 9, 10, 15, 16};
        constexpr int LEV[13] = {0, 0, 0, 0,  0,  1, 1, 1,  1,  2, 2,  2,  2};
        const float* Wls[3] = {W0, W1, W2};
        const float* bls[3] = {b0, b1, b2};
        float wx[3], wy[3], wsv[3], wb[3];
#pragma unroll
        for (int L = 0; L < 3; ++L) {
            wx[L] = Wls[L][lane * 3 + 0];
            wy[L] = Wls[L][lane * 3 + 1];
            wsv[L] = Wls[L][lane * 3 + 2];
            wb[L] = bls[L][lane];
        }

#pragma unroll
        for (int half = 0; half < 2; ++half) {
            int s = 2 * w + half;
            float mnxh = mnx_h[half], mnyh = mny_h[half];
            float ixh = ix_h[half], iyh = iy_h[half];

            float mj[13], sj[13];
            float msum[3] = {0.f, 0.f, 0.f};
#pragma unroll
            for (int q = 0; q < 13; ++q) {
                int j = JL[q];
                int L = LEV[q];
                float4 pv = Praw[s][j];                  // b128 broadcast
                float px = (pv.x - mnxh) * ixh;          // same-wave RAW
                float py = (pv.y - mnyh) * iyh;
                float ps = pv.z;
                float h = fmaxf(px * wx[L] + py * wy[L] + ps * wsv[L] + wb[L], 0.f);
                float m = h * ps;
                mj[q] = m;
                sj[q] = ps;
                msum[L] += m;
            }
#pragma unroll
            for (int q = 0; q < 13; ++q) {
                featT[q][s][lane] = f2bu((msum[LEV[q]] - mj[q]) * sj[q]);
            }
            // H-part: Hsum_L = (CNT_L - 1) * msum_L (validated r6)
            finS[s][0 * 128 + lane] = f2bu(4.f * msum[0] * (1.f / 17.f));
            finS[s][1 * 128 + lane] = f2bu(3.f * msum[1] * (1.f / 17.f));
            finS[s][2 * 128 + lane] = f2bu(3.f * msum[2] * (1.f / 17.f));
        }
    }
    __syncthreads();

    // ============ phase 2: wave = (t-tile, level-set), MFMA a/c ============
    {
        float4v binit = (float4v){bet, bet, bet, bet};
        if (parity == 0) {
            do_lvl_mfma<0, 5, 4, 0>(featT, lane, t2, bA, bC, binit, finS);
        } else {
            do_lvl_mfma<5, 4, 9, 1>(featT, lane, t2, bA, bC, binit, finS);
            do_lvl_mfma<9, 4, 4, 2>(featT, lane, t2, bA, bC, binit, finS);
        }
    }
    __syncthreads();

    // ====== phase 3: wave = n-tile w; out = finS @ wpB^T + bp (MFMA) =======
    {
        const short8v* bptr = (const short8v*)(wpB + (size_t)o3 * 384 + kq8);
        float4v acc = (float4v){bvout, bvout, bvout, bvout};
#pragma unroll
        for (int kt = 0; kt < 12; ++kt) {
            short8v a = *(const short8v*)&finS[lane & 15][kt * 32 + kq8];
            short8v b = bptr[kt * 4];
            acc = __builtin_amdgcn_mfma_f32_16x16x32_bf16(a, b, acc, 0, 0, 0);
        }
        int srow = (lane >> 4) * 4;
#pragma unroll
        for (int r = 0; r < 4; ++r) {
            out[(size_t)(sampBase + srow + r) * 128 + o3] = acc[r];
        }
    }
}

// ===========================================================================
// Fallback: validated round-2 fused kernel (used only if ws too small).
// ===========================================================================
template <int LI, int CNT, int OTH>
DEVINL void do_level_f(int w, int lane,
                       const float* __restrict__ Wl, const float* __restrict__ bl,
                       float mnx, float ix, float mny, float iy,
                       const float (*Praw)[17][3],
                       float (*featS)[64][8],
                       const float2 (*WW)[64],
                       const float* beS,
                       float (*finS)[384]) {
    constexpr int SUBJ[3][5] = {{0, 5, 6, 11, 12}, {7, 8, 13, 14, 16}, {9, 10, 15, 16, 16}};
    float w0 = Wl[lane * 3 + 0], w1 = Wl[lane * 3 + 1], w2 = Wl[lane * 3 + 2], bb = bl[lane];
    float mj[CNT], sj[CNT];
    float msum = 0.f;
#pragma unroll
    for (int jj = 0; jj < CNT; ++jj) {
        int j = SUBJ[LI][jj];
        float px = (Praw[w][j][0] - mnx) * ix;
        float py = (Praw[w][j][1] - mny) * iy;
        float ps = Praw[w][j][2];
        float h = fmaxf(px * w0 + py * w1 + ps * w2 + bb, 0.f);
        float m = h * ps;
        mj[jj] = m; sj[jj] = ps; msum += m;
    }
#pragma unroll
    for (int jj = 0; jj < CNT; ++jj) featS[w][lane][jj] = (msum - mj[jj]) * sj[jj];
    float Hsum = (float)(CNT - 1) * msum;
    __syncthreads();
    float a_[CNT], c_[CNT];
    float bet = beS[lane];
#pragma unroll
    for (int jj = 0; jj < CNT; ++jj) { a_[jj] = bet; c_[jj] = 0.f; }
#pragma unroll 4
    for (int d = 0; d < 64; ++d) {
        float2 wv = WW[d][lane];
        const float* fr = &featS[w][d][0];
        float4 f4 = *(const float4*)fr;
        float f[5];
        f[0] = f4.x; f[1] = f4.y; f[2] = f4.z; f[3] = f4.w; f[4] = 0.f;
        if constexpr (CNT > 4) f[4] = fr[4];
#pragma unroll
        for (int jj = 0; jj < CNT; ++jj) {
            a_[jj] = fmaf(wv.x, f[jj], a_[jj]);
            c_[jj] = fmaf(wv.y, f[jj], c_[jj]);
        }
    }
    __syncthreads();
    float zsum = 0.f;
#pragma unroll
    for (int jj = 0; jj < CNT; ++jj) {
        float z = fmaxf(a_[jj], 0.f);
#pragma unroll
        for (int kk = 0; kk < CNT; ++kk)
            if (kk != jj) z = fmaxf(z, a_[jj] + c_[kk]);
        zsum += z;
    }
    float zo = 0.f;
#pragma unroll
    for (int kk = 0; kk < CNT; ++kk) zo = fmaxf(zo, bet + c_[kk]);
    zsum += (float)OTH * zo;
    finS[w][LI * 128 + lane] = Hsum * (1.f / 17.f);
    finS[w][LI * 128 + 64 + lane] = zsum * (1.f / 17.f);
}

__global__ __launch_bounds__(256) void hse_fused_kernel(
    const float* __restrict__ kp, const float* __restrict__ sc,
    const float* __restrict__ W0, const float* __restrict__ b0,
    const float* __restrict__ W1, const float* __restrict__ b1,
    const float* __restrict__ W2, const float* __restrict__ b2,
    const float* __restrict__ We, const float* __restrict__ be,
    const float* __restrict__ Wp, const float* __restrict__ bp,
    float* __restrict__ out) {
    __shared__ float2 WW[64][64];
    __shared__ float beS[64];
    __shared__ float Praw[4][17][3];
    __shared__ float featS[4][64][8];
    __shared__ float finS[4][384];

    int tid = threadIdx.x;
    int w = tid >> 6;
    int lane = tid & 63;
    int sample = blockIdx.x * 4 + w;

    for (int i = tid; i < 4096; i += 256) {
        int t = i >> 6, d = i & 63;
        float wA = We[t * 128 + d];
        float wB = We[t * 128 + 64 + d];
        WW[d][t] = make_float2(wA - wB, wB);
    }
    if (tid < 64) beS[tid] = be[tid];
    if (lane < 17) {
        size_t base = (size_t)sample * 17 + lane;
        float2 xy = *(const float2*)(kp + base * 2);
        Praw[w][lane][0] = xy.x;
        Praw[w][lane][1] = xy.y;
        Praw[w][lane][2] = sc[base];
    }
    __syncthreads();

    float mnx = 1e30f, mxx = -1e30f, mny = 1e30f, mxy = -1e30f;
    for (int j = 0; j < 17; ++j) {
        float x = Praw[w][j][0], y = Praw[w][j][1];
        mnx = fminf(mnx, x); mxx = fmaxf(mxx, x);
        mny = fminf(mny, y); mxy = fmaxf(mxy, y);
    }
    float ix = 1.f / (mxx - mnx + 1e-6f);
    float iy = 1.f / (mxy - mny + 1e-6f);

    do_level_f<0, 5, 4>(w, lane, W0, b0, mnx, ix, mny, iy, Praw, featS, WW, beS, finS);
    do_level_f<1, 4, 9>(w, lane, W1, b1, mnx, ix, mny, iy, Praw, featS, WW, beS, finS);
    do_level_f<2, 4, 4>(w, lane, W2, b2, mnx, ix, mny, iy, Praw, featS, WW, beS, finS);
    __syncthreads();

    float acc0 = bp[lane];
    float acc1 = bp[64 + lane];
    const float* r0 = Wp + (size_t)lane * 384;
    const float* r1 = Wp + (size_t)(64 + lane) * 384;
    const float* fv = finS[w];
#pragma unroll 8
    for (int e = 0; e < 384; e += 4) {
        float4 wa = *(const float4*)(r0 + e);
        float4 wb = *(const float4*)(r1 + e);
        float4 ffv = *(const float4*)(fv + e);
        acc0 = fmaf(wa.x, ffv.x, acc0);
        acc0 = fmaf(wa.y, ffv.y, acc0);
        acc0 = fmaf(wa.z, ffv.z, acc0);
        acc0 = fmaf(wa.w, ffv.w, acc0);
        acc1 = fmaf(wb.x, ffv.x, acc1);
        acc1 = fmaf(wb.y, ffv.y, acc1);
        acc1 = fmaf(wb.z, ffv.z, acc1);
        acc1 = fmaf(wb.w, ffv.w, acc1);
    }
    out[(size_t)sample * 128 + lane] = acc0;
    out[(size_t)sample * 128 + 64 + lane] = acc1;
}

extern "C" void kernel_launch(void* const* d_in, const int* in_sizes, int n_in,
                              void* d_out, int out_size, void* d_ws, size_t ws_size,
                              hipStream_t stream) {
    const float* kp = (const float*)d_in[0];
    const float* sc = (const float*)d_in[1];
    const float* W0 = (const float*)d_in[2];
    const float* b0 = (const float*)d_in[3];
    const float* W1 = (const float*)d_in[4];
    const float* b1 = (const float*)d_in[5];
    const float* W2 = (const float*)d_in[6];
    const float* b2 = (const float*)d_in[7];
    const float* We = (const float*)d_in[8];
    const float* be = (const float*)d_in[9];
    const float* Wp = (const float*)d_in[10];
    const float* bp = (const float*)d_in[11];
    float* out = (float*)d_out;

    int N = in_sizes[0] / 34;  // keypoints N*17*2 -> 8192
    size_t need = 49152 * sizeof(unsigned short);

    if (ws_size >= need) {
        unsigned short* wpB = (unsigned short*)d_ws;
        hipLaunchKernelGGL(cvt_wp_kernel, dim3(48), dim3(256), 0, stream, Wp, wpB);
        hipLaunchKernelGGL(hse_one_kernel, dim3(N / 16), dim3(512), 0, stream,
                           kp, sc, W0, b0, W1, b1, W2, b2, We, be, wpB, bp, out);
    } else {
        hipLaunchKernelGGL(hse_fused_kernel, dim3(N / 4), dim3(256), 0, stream,
                           kp, sc, W0, b0, W1, b1, W2, b2, We, be, Wp, bp, out);
    }
}